// Round 1
// baseline (37.113 us; speedup 1.0000x reference)
//
#include <hip/hip_runtime.h>

#define B 8
#define K 8
#define H 384
#define W 384
#define HW (H*W)                 // 147456 pixels per batch
#define NCHUNK 72                // chunks per batch for the reduction
#define GROUPS_PER_B (HW/4)      // 36864 float4-groups per batch

// ws layout (floats):
//   [0, B*NCHUNK*32)                     : reduction partials (per b,chunk: 8k x 4 comps)
//   [WS_PK, WS_PK + B*K*12)              : per-(b,k) params  (M 9, c 3)
//   [WS_PB, WS_PB + B*12)                : per-b params      (Rc 9, d 3)
#define N_PARTIALS (B*NCHUNK*32)         // 18432
#define WS_PK N_PARTIALS
#define WS_PB (WS_PK + B*K*12)           // 18432 + 768 = 19200

__device__ __forceinline__ void euler2mat(float ax, float ay, float az, float R[9]) {
    float cx = cosf(ax), sx = sinf(ax);
    float cy = cosf(ay), sy = sinf(ay);
    float cz = cosf(az), sz = sinf(az);
    // R = xmat @ ymat @ zmat
    R[0] = cy*cz;              R[1] = -cy*sz;             R[2] = sy;
    R[3] = cx*sz + sx*sy*cz;   R[4] = cx*cz - sx*sy*sz;   R[5] = -sx*cy;
    R[6] = sx*sz - cx*sy*cz;   R[7] = sx*cz + cx*sy*sz;   R[8] = cx*cy;
}

// ---------------- Stage A: per-(b,k) weighted sums over pixels ----------------
// grid (NCHUNK, B), 256 threads; each thread handles 2 float4 groups (8 pixels).
__global__ __launch_bounds__(256) void k_reduce(const float* __restrict__ mask,
                                                const float* __restrict__ depth,
                                                float* __restrict__ ws) {
    const int chunk = blockIdx.x;
    const int b = blockIdx.y;
    const int tid = threadIdx.x;

    float acc[32];
#pragma unroll
    for (int i = 0; i < 32; ++i) acc[i] = 0.f;

    const float4* d4 = (const float4*)(depth + (size_t)b * HW);
    const float inv = 2.f / W;

#pragma unroll
    for (int r = 0; r < 2; ++r) {
        int g = chunk * 512 + r * 256 + tid;       // float4-group index in [0, 36864)
        float4 dv = d4[g];
        int i0 = g * 4;
        int h = i0 / W;
        int w0 = i0 - h * W;                        // 4 | W so all 4 pixels share h
        float py = 2.f * (h + 0.5f) * (1.f / H) - 1.f;
        float px0 = 2.f * (w0 + 0.5f) * (1.f / W) - 1.f;
        float px[4] = {px0, px0 + inv, px0 + 2.f*inv, px0 + 3.f*inv};
        float dd[4] = {dv.x, dv.y, dv.z, dv.w};
#pragma unroll
        for (int k = 0; k < K; ++k) {
            float4 mv = ((const float4*)(mask + ((size_t)(b*K + k)) * HW))[g];
            float mm[4] = {mv.x, mv.y, mv.z, mv.w};
#pragma unroll
            for (int j = 0; j < 4; ++j) {
                float m = mm[j];
                float t = m * dd[j];
                acc[k*4 + 0] += m;
                acc[k*4 + 1] += t * px[j];
                acc[k*4 + 2] += t * py;
                acc[k*4 + 3] += t;
            }
        }
    }

    // deterministic reduction: wave shuffle then LDS across 4 waves
    __shared__ float sdata[4 * 32];
    int lane = tid & 63, wid = tid >> 6;
#pragma unroll
    for (int i = 0; i < 32; ++i) {
        float v = acc[i];
        for (int off = 32; off > 0; off >>= 1) v += __shfl_down(v, off);
        if (lane == 0) sdata[wid * 32 + i] = v;
    }
    __syncthreads();
    if (tid < 32) {
        float v = sdata[tid] + sdata[32 + tid] + sdata[64 + tid] + sdata[96 + tid];
        ws[((b * NCHUNK + chunk) << 5) + tid] = v;
    }
}

// ---------------- Stage B: fold partials -> per-(b,k) affine params ----------------
// 1 block, 64 threads (one per (b,k)); threads 0..7 also do the per-b camera params.
__global__ void k_params(const float* __restrict__ T, const float* __restrict__ Tc,
                         float* __restrict__ ws) {
    int t = threadIdx.x;
    if (t < 64) {
        int b = t >> 3, k = t & 7;
        float s0 = 0.f, s1 = 0.f, s2 = 0.f, s3 = 0.f;
        for (int ch = 0; ch < NCHUNK; ++ch) {
            const float* src = ws + ((b * NCHUNK + ch) << 5) + (k << 2);
            s0 += src[0]; s1 += src[1]; s2 += src[2]; s3 += src[3];
        }
        float mass = s0 + 1e-6f;
        float p0 = s1 / mass, p1 = s2 / mass, p2 = s3 / mass;
        const float* Tk = T + t * 6;
        float R[9];
        euler2mat(Tk[3], Tk[4], Tk[5], R);
        float Rp0 = R[0]*p0 + R[1]*p1 + R[2]*p2;
        float Rp1 = R[3]*p0 + R[4]*p1 + R[5]*p2;
        float Rp2 = R[6]*p0 + R[7]*p1 + R[8]*p2;
        float* o = ws + WS_PK + t * 12;
        o[0] = R[0] - 1.f; o[1] = R[1];       o[2] = R[2];
        o[3] = R[3];       o[4] = R[4] - 1.f; o[5] = R[5];
        o[6] = R[6];       o[7] = R[7];       o[8] = R[8] - 1.f;
        o[9]  = p0 + Tk[0] - Rp0;
        o[10] = p1 + Tk[1] - Rp1;
        o[11] = p2 + Tk[2] - Rp2;
    }
    if (t < 8) {
        const float* Tb = Tc + t * 9;
        float R[9];
        euler2mat(Tb[3], Tb[4], Tb[5], R);
        float pc0 = Tb[6], pc1 = Tb[7], pc2 = Tb[8];
        float* o = ws + WS_PB + t * 12;
#pragma unroll
        for (int i = 0; i < 9; ++i) o[i] = R[i];
        o[9]  = pc0 + Tb[0] - (R[0]*pc0 + R[1]*pc1 + R[2]*pc2);
        o[10] = pc1 + Tb[1] - (R[3]*pc0 + R[4]*pc1 + R[5]*pc2);
        o[11] = pc2 + Tb[2] - (R[6]*pc0 + R[7]*pc1 + R[8]*pc2);
    }
}

// ---------------- Stage C: per-pixel transform + perspective divide ----------------
// grid (GROUPS_PER_B/256, B), 256 threads; 1 float4 group (4 pixels) per thread.
__global__ __launch_bounds__(256) void k_flow(const float* __restrict__ mask,
                                              const float* __restrict__ depth,
                                              const float* __restrict__ ws,
                                              float* __restrict__ out) {
    const int b = blockIdx.y;
    const int tid = threadIdx.x;

    __shared__ float sp[108];                 // 8 x 12 per-k params + 12 camera params
    if (tid < 96) sp[tid] = ws[WS_PK + b * 96 + tid];
    else if (tid < 108) sp[tid] = ws[WS_PB + b * 12 + (tid - 96)];
    __syncthreads();

    int g = blockIdx.x * 256 + tid;           // [0, 36864)
    int i0 = g * 4;
    int h = i0 / W;
    int w0 = i0 - h * W;
    float py = 2.f * (h + 0.5f) * (1.f / H) - 1.f;
    const float inv = 2.f / W;
    float px0 = 2.f * (w0 + 0.5f) * (1.f / W) - 1.f;

    float4 dv = ((const float4*)(depth + (size_t)b * HW))[g];
    float4 mf[K];
#pragma unroll
    for (int k = 0; k < K; ++k)
        mf[k] = ((const float4*)(mask + ((size_t)(b*K + k)) * HW))[g];

    float dd[4] = {dv.x, dv.y, dv.z, dv.w};
    float res[8];
#pragma unroll
    for (int j = 0; j < 4; ++j) {
        float px = px0 + j * inv;
        float d = dd[j];
        float wx = d * px, wy = d * py, wz = d;
        float ax = wx, ay = wy, az = wz;
#pragma unroll
        for (int k = 0; k < K; ++k) {
            const float* P = sp + k * 12;
            float m = (j == 0) ? mf[k].x : (j == 1) ? mf[k].y : (j == 2) ? mf[k].z : mf[k].w;
            float rx = P[0]*wx + P[1]*wy + P[2]*wz + P[9];
            float ry = P[3]*wx + P[4]*wy + P[5]*wz + P[10];
            float rz = P[6]*wx + P[7]*wy + P[8]*wz + P[11];
            ax += m * rx; ay += m * ry; az += m * rz;
        }
        const float* C = sp + 96;
        float ox = C[0]*ax + C[1]*ay + C[2]*az + C[9];
        float oy = C[3]*ax + C[4]*ay + C[5]*az + C[10];
        float oz = C[6]*ax + C[7]*ay + C[8]*az + C[11];
        res[j*2 + 0] = ox / oz - px;
        res[j*2 + 1] = oy / oz - py;
    }

    float4* o4 = (float4*)(out + ((size_t)b * HW + i0) * 2);
    o4[0] = make_float4(res[0], res[1], res[2], res[3]);
    o4[1] = make_float4(res[4], res[5], res[6], res[7]);
}

extern "C" void kernel_launch(void* const* d_in, const int* in_sizes, int n_in,
                              void* d_out, int out_size, void* d_ws, size_t ws_size,
                              hipStream_t stream) {
    // inputs: im (unused), mask, depth, T, Tc — all float32
    const float* mask  = (const float*)d_in[1];
    const float* depth = (const float*)d_in[2];
    const float* T     = (const float*)d_in[3];
    const float* Tc    = (const float*)d_in[4];
    float* ws  = (float*)d_ws;
    float* out = (float*)d_out;

    k_reduce<<<dim3(NCHUNK, B), 256, 0, stream>>>(mask, depth, ws);
    k_params<<<1, 64, 0, stream>>>(T, Tc, ws);
    k_flow<<<dim3(GROUPS_PER_B / 256, B), 256, 0, stream>>>(mask, depth, ws, out);
}

// Round 2
// 27.164 us; speedup vs baseline: 1.3663x; 1.3663x over previous
//
#include <hip/hip_runtime.h>

#define B 8
#define K 8
#define H 384
#define W 384
#define HW (H*W)                 // 147456 pixels per batch
#define NCPP 16                  // chunks per (b,k) plane in stage A
#define GROUPS_PER_B (HW/4)      // 36864 float4-groups per batch

// ws layout (floats):
//   [0, B*K*NCPP*4)           : stage-A partials, per (b,k,chunk): {sum_m, sum_mdx, sum_mdy, sum_md}
//   [WS_PK, +B*K*12)          : per-(b,k) params (M 9, c 3)
//   [WS_PB, +B*12)            : per-b camera params (Rc 9, d 3)
#define WS_PK (B*K*NCPP*4)               // 4096
#define WS_PB (WS_PK + B*K*12)           // 4864

__device__ __forceinline__ void euler2mat(float ax, float ay, float az, float R[9]) {
    float cx = cosf(ax), sx = sinf(ax);
    float cy = cosf(ay), sy = sinf(ay);
    float cz = cosf(az), sz = sinf(az);
    // R = xmat @ ymat @ zmat
    R[0] = cy*cz;              R[1] = -cy*sz;             R[2] = sy;
    R[3] = cx*sz + sx*sy*cz;   R[4] = cx*cz - sx*sy*sz;   R[5] = -sx*cy;
    R[6] = sx*sz - cx*sy*cz;   R[7] = sx*cz + cx*sy*sz;   R[8] = cx*cy;
}

// ---------------- Stage A: per-(b,k) weighted sums ----------------
// One (b,k) mask plane per block-column: grid (NCPP, K, B), 256 threads,
// 9 float4-groups per thread, 4-float accumulator -> cheap reduction.
__global__ __launch_bounds__(256) void k_reduce(const float* __restrict__ mask,
                                                const float* __restrict__ depth,
                                                float* __restrict__ ws) {
    const int chunk = blockIdx.x, k = blockIdx.y, b = blockIdx.z;
    const int tid = threadIdx.x;

    const float4* m4 = (const float4*)(mask + ((size_t)(b*K + k)) * HW);
    const float4* d4 = (const float4*)(depth + (size_t)b * HW);

    float s0 = 0.f, s1 = 0.f, s2 = 0.f, s3 = 0.f;
    const float inv = 2.f / W;

#pragma unroll
    for (int r = 0; r < 9; ++r) {
        int g = (chunk * 9 + r) * 256 + tid;   // float4-group in [0, 36864)
        float4 mv = m4[g];
        float4 dv = d4[g];
        int i0 = g * 4;
        int h = i0 / W;
        int w0 = i0 - h * W;                   // 4 | W: all 4 pixels share row h
        float py = 2.f * (h + 0.5f) * (1.f / H) - 1.f;
        float px0 = 2.f * (w0 + 0.5f) * (1.f / W) - 1.f;
        float mm[4] = {mv.x, mv.y, mv.z, mv.w};
        float dd[4] = {dv.x, dv.y, dv.z, dv.w};
#pragma unroll
        for (int j = 0; j < 4; ++j) {
            float m = mm[j];
            float t = m * dd[j];
            float px = px0 + j * inv;
            s0 += m; s1 += t * px; s2 += t * py; s3 += t;
        }
    }

    // deterministic: wave butterfly (4 values) then LDS across 4 waves
    for (int off = 32; off > 0; off >>= 1) {
        s0 += __shfl_down(s0, off);
        s1 += __shfl_down(s1, off);
        s2 += __shfl_down(s2, off);
        s3 += __shfl_down(s3, off);
    }
    __shared__ float sd[16];
    int lane = tid & 63, wid = tid >> 6;
    if (lane == 0) { sd[wid*4+0]=s0; sd[wid*4+1]=s1; sd[wid*4+2]=s2; sd[wid*4+3]=s3; }
    __syncthreads();
    if (tid < 4) {
        float v = sd[tid] + sd[4 + tid] + sd[8 + tid] + sd[12 + tid];
        ws[(((b*K + k) * NCPP) + chunk) * 4 + tid] = v;
    }
}

// ---------------- Stage B: fold partials -> affine params ----------------
__global__ void k_params(const float* __restrict__ T, const float* __restrict__ Tc,
                         float* __restrict__ ws) {
    int t = threadIdx.x;
    if (t < 64) {
        float s0 = 0.f, s1 = 0.f, s2 = 0.f, s3 = 0.f;
        for (int ch = 0; ch < NCPP; ++ch) {
            const float* src = ws + (t * NCPP + ch) * 4;   // t == b*K+k
            s0 += src[0]; s1 += src[1]; s2 += src[2]; s3 += src[3];
        }
        float mass = s0 + 1e-6f;
        float p0 = s1 / mass, p1 = s2 / mass, p2 = s3 / mass;
        const float* Tk = T + t * 6;
        float R[9];
        euler2mat(Tk[3], Tk[4], Tk[5], R);
        float Rp0 = R[0]*p0 + R[1]*p1 + R[2]*p2;
        float Rp1 = R[3]*p0 + R[4]*p1 + R[5]*p2;
        float Rp2 = R[6]*p0 + R[7]*p1 + R[8]*p2;
        float* o = ws + WS_PK + t * 12;
        o[0] = R[0] - 1.f; o[1] = R[1];       o[2] = R[2];
        o[3] = R[3];       o[4] = R[4] - 1.f; o[5] = R[5];
        o[6] = R[6];       o[7] = R[7];       o[8] = R[8] - 1.f;
        o[9]  = p0 + Tk[0] - Rp0;
        o[10] = p1 + Tk[1] - Rp1;
        o[11] = p2 + Tk[2] - Rp2;
    }
    if (t < 8) {
        const float* Tb = Tc + t * 9;
        float R[9];
        euler2mat(Tb[3], Tb[4], Tb[5], R);
        float pc0 = Tb[6], pc1 = Tb[7], pc2 = Tb[8];
        float* o = ws + WS_PB + t * 12;
#pragma unroll
        for (int i = 0; i < 9; ++i) o[i] = R[i];
        o[9]  = pc0 + Tb[0] - (R[0]*pc0 + R[1]*pc1 + R[2]*pc2);
        o[10] = pc1 + Tb[1] - (R[3]*pc0 + R[4]*pc1 + R[5]*pc2);
        o[11] = pc2 + Tb[2] - (R[6]*pc0 + R[7]*pc1 + R[8]*pc2);
    }
}

// ---------------- Stage C: per-pixel transform + perspective divide ----------------
__global__ __launch_bounds__(256) void k_flow(const float* __restrict__ mask,
                                              const float* __restrict__ depth,
                                              const float* __restrict__ ws,
                                              float* __restrict__ out) {
    const int b = blockIdx.y;
    const int tid = threadIdx.x;

    __shared__ float sp[108];                 // 8 x 12 per-k params + 12 camera
    if (tid < 96) sp[tid] = ws[WS_PK + b * 96 + tid];
    else if (tid < 108) sp[tid] = ws[WS_PB + b * 12 + (tid - 96)];
    __syncthreads();

    int g = blockIdx.x * 256 + tid;           // [0, 36864)
    int i0 = g * 4;
    int h = i0 / W;
    int w0 = i0 - h * W;
    float py = 2.f * (h + 0.5f) * (1.f / H) - 1.f;
    const float inv = 2.f / W;
    float px0 = 2.f * (w0 + 0.5f) * (1.f / W) - 1.f;

    float4 dv = ((const float4*)(depth + (size_t)b * HW))[g];
    float4 mf[K];
#pragma unroll
    for (int k = 0; k < K; ++k)
        mf[k] = ((const float4*)(mask + ((size_t)(b*K + k)) * HW))[g];

    float dd[4] = {dv.x, dv.y, dv.z, dv.w};
    float res[8];
#pragma unroll
    for (int j = 0; j < 4; ++j) {
        float px = px0 + j * inv;
        float d = dd[j];
        float wx = d * px, wy = d * py, wz = d;
        float ax = wx, ay = wy, az = wz;
#pragma unroll
        for (int k = 0; k < K; ++k) {
            const float* P = sp + k * 12;
            float m = (j == 0) ? mf[k].x : (j == 1) ? mf[k].y : (j == 2) ? mf[k].z : mf[k].w;
            float rx = P[0]*wx + P[1]*wy + P[2]*wz + P[9];
            float ry = P[3]*wx + P[4]*wy + P[5]*wz + P[10];
            float rz = P[6]*wx + P[7]*wy + P[8]*wz + P[11];
            ax += m * rx; ay += m * ry; az += m * rz;
        }
        const float* C = sp + 96;
        float ox = C[0]*ax + C[1]*ay + C[2]*az + C[9];
        float oy = C[3]*ax + C[4]*ay + C[5]*az + C[10];
        float oz = C[6]*ax + C[7]*ay + C[8]*az + C[11];
        res[j*2 + 0] = ox / oz - px;
        res[j*2 + 1] = oy / oz - py;
    }

    float4* o4 = (float4*)(out + ((size_t)b * HW + i0) * 2);
    o4[0] = make_float4(res[0], res[1], res[2], res[3]);
    o4[1] = make_float4(res[4], res[5], res[6], res[7]);
}

extern "C" void kernel_launch(void* const* d_in, const int* in_sizes, int n_in,
                              void* d_out, int out_size, void* d_ws, size_t ws_size,
                              hipStream_t stream) {
    // inputs: im (unused), mask, depth, T, Tc — all float32
    const float* mask  = (const float*)d_in[1];
    const float* depth = (const float*)d_in[2];
    const float* T     = (const float*)d_in[3];
    const float* Tc    = (const float*)d_in[4];
    float* ws  = (float*)d_ws;
    float* out = (float*)d_out;

    k_reduce<<<dim3(NCPP, K, B), 256, 0, stream>>>(mask, depth, ws);
    k_params<<<1, 64, 0, stream>>>(T, Tc, ws);
    k_flow<<<dim3(GROUPS_PER_B / 256, B), 256, 0, stream>>>(mask, depth, ws, out);
}